// Round 2
// baseline (563.492 us; speedup 1.0000x reference)
//
#include <hip/hip_runtime.h>

#define NUM_USERS 80000
#define NUM_ITEMS 40000
#define NUM_NODES 120000
#define DIM 64
#define ALPHA_C 0.8f

typedef unsigned short u16;
typedef unsigned int u32;
typedef int   i2v __attribute__((ext_vector_type(2)));
typedef u32   u4v __attribute__((ext_vector_type(4)));
typedef float f4v __attribute__((ext_vector_type(4)));

// fp32 -> bf16 round-nearest-even
__device__ __forceinline__ u16 f2bf(float f) {
    union { float f; u32 i; } v;
    v.f = f;
    u32 i = v.i;
    u32 r = (i + 0x7FFFu + ((i >> 16) & 1u)) >> 16;
    return (u16)r;
}
__device__ __forceinline__ float lo_bf(u32 u) { return __uint_as_float(u << 16); }
__device__ __forceinline__ float hi_bf(u32 u) { return __uint_as_float(u & 0xffff0000u); }

// accumulate 8 bf16 (packed in uint4) * v into acc[8]
__device__ __forceinline__ void acc8(float* __restrict__ acc, float v, uint4 q) {
    const u32* p = (const u32*)&q;
#pragma unroll
    for (int k = 0; k < 4; ++k) {
        u32 u = p[k];
        acc[2 * k]     = fmaf(v, lo_bf(u), acc[2 * k]);
        acc[2 * k + 1] = fmaf(v, hi_bf(u), acc[2 * k + 1]);
    }
}

__device__ __forceinline__ uint4 ldrow(const u16* __restrict__ x, int c, int li) {
    return *((const uint4*)(x + (size_t)c * DIM) + li);
}

__device__ __forceinline__ i2v ntl_e(const i2v* __restrict__ p) {
    return __builtin_nontemporal_load(p);
}

// ---------------------------------------------------------------------------
// Depth-4 software-pipelined segment gather over a PACKED {col,val} stream.
// 8-lane group walks its segment. Per iteration: nt-load edge-pair p, issue
// row gathers for pair p-2, consume pair p-4. Edge loads sit 2 iterations
// ahead of their gather so the vmcnt wait for addresses never drains the
// in-flight row gathers. Edge stream is single-use -> nontemporal loads
// (keep gather-table lines in L2 instead).
// If SUMV, also accumulates the sum of val into *vsum (accumulation order
// is exactly edge order 0,1,2,... -- bitwise identical to prior rounds).
// ---------------------------------------------------------------------------
template <bool SUMV>
__device__ __forceinline__ void seg_pipe(const i2v* __restrict__ ep0,
                                         int start, int end,
                                         const u16* __restrict__ x,
                                         int li,
                                         float* __restrict__ acc,
                                         float* __restrict__ vsum) {
    const int n = end - start;
    const i2v* ep = ep0 + start;
    float s = 0.f;
    const int np = n >> 1;
    if (np >= 4) {
        i2v ea0 = ntl_e(ep + 0), ea1 = ntl_e(ep + 1);
        i2v eb0 = ntl_e(ep + 2), eb1 = ntl_e(ep + 3);
        i2v ec0 = ntl_e(ep + 4), ec1 = ntl_e(ep + 5);
        i2v ed0 = ntl_e(ep + 6), ed1 = ntl_e(ep + 7);
        uint4 xa0 = ldrow(x, ea0.x, li), xa1 = ldrow(x, ea1.x, li);
        uint4 xb0 = ldrow(x, eb0.x, li), xb1 = ldrow(x, eb1.x, li);
        for (int p = 4; p < np; ++p) {
            // E: prefetch edge pair p (2 iterations ahead of its gather)
            i2v ee0 = ntl_e(ep + 2 * p);
            i2v ee1 = ntl_e(ep + 2 * p + 1);
            // G: issue row gathers for pair p-2 (edges arrived long ago)
            uint4 xc0 = ldrow(x, ec0.x, li);
            uint4 xc1 = ldrow(x, ec1.x, li);
            // C: consume pair p-4 (rows issued 2 iterations ago)
            float va0 = __int_as_float(ea0.y), va1 = __int_as_float(ea1.y);
            acc8(acc, va0, xa0);
            acc8(acc, va1, xa1);
            if (SUMV) s += va0 + va1;
            // shift pipeline
            ea0 = eb0; ea1 = eb1; eb0 = ec0; eb1 = ec1;
            ec0 = ed0; ec1 = ed1; ed0 = ee0; ed1 = ee1;
            xa0 = xb0; xa1 = xb1; xb0 = xc0; xb1 = xc1;
        }
        // drain: pipe holds pairs A(rows xa), B(rows xb), C(cols ec), D(cols ed)
        uint4 xc0 = ldrow(x, ec0.x, li), xc1 = ldrow(x, ec1.x, li);
        uint4 xd0 = ldrow(x, ed0.x, li), xd1 = ldrow(x, ed1.x, li);
        {
            float va0 = __int_as_float(ea0.y), va1 = __int_as_float(ea1.y);
            acc8(acc, va0, xa0); acc8(acc, va1, xa1);
            if (SUMV) s += va0 + va1;
        }
        {
            float vb0 = __int_as_float(eb0.y), vb1 = __int_as_float(eb1.y);
            acc8(acc, vb0, xb0); acc8(acc, vb1, xb1);
            if (SUMV) s += vb0 + vb1;
        }
        {
            float vc0 = __int_as_float(ec0.y), vc1 = __int_as_float(ec1.y);
            acc8(acc, vc0, xc0); acc8(acc, vc1, xc1);
            if (SUMV) s += vc0 + vc1;
        }
        {
            float vd0 = __int_as_float(ed0.y), vd1 = __int_as_float(ed1.y);
            acc8(acc, vd0, xd0); acc8(acc, vd1, xd1);
            if (SUMV) s += vd0 + vd1;
        }
        if (n & 1) {
            i2v eq = ntl_e(ep + n - 1);
            float v = __int_as_float(eq.y);
            uint4 xq = ldrow(x, eq.x, li);
            acc8(acc, v, xq);
            if (SUMV) s += v;
        }
    } else {
        for (int e = 0; e < n; ++e) {
            i2v eq = ntl_e(ep + e);
            float v = __int_as_float(eq.y);
            uint4 xq = ldrow(x, eq.x, li);
            acc8(acc, v, xq);
            if (SUMV) s += v;
        }
    }
    if (SUMV) *vsum = s;
}

// ---------------------------------------------------------------------------
// K1: fused theta-softmax + exp_v + path-stream pack.
//     pev[i] = { p_col[i], exp(dot(p_counts[i,0:6], softmax(theta))) }
//     Every thread recomputes the 6-element softmax (expression-identical to
//     the old two-kernel version -> bitwise-same values).
// ---------------------------------------------------------------------------
__global__ void k_expv_pack(const float* __restrict__ p_counts,
                            const float* __restrict__ theta,
                            const int* __restrict__ p_col,
                            i2v* __restrict__ pev, int E) {
    int i = blockIdx.x * blockDim.x + threadIdx.x;
    if (i >= E) return;
    float m = -1e30f;
    for (int k = 0; k < 6; ++k) m = fmaxf(m, theta[k]);
    float e[6];
    float s = 0.f;
    for (int k = 0; k < 6; ++k) { e[k] = expf(theta[k] - m); s += e[k]; }
    float w0 = e[0] / s, w1 = e[1] / s, w2 = e[2] / s,
          w3 = e[3] / s, w4 = e[4] / s, w5 = e[5] / s;
    const float* c = p_counts + (size_t)i * 6;
    float v = c[0] * w0 + c[1] * w1 + c[2] * w2 +
              c[3] * w3 + c[4] * w4 + c[5] * w5;
    i2v o;
    o.x = __builtin_nontemporal_load(p_col + i);
    o.y = __float_as_int(expf(v));
    __builtin_nontemporal_store(o, pev + i);
}

// ---------------------------------------------------------------------------
// K2: all CSR row_ptr arrays in one launch (rows sorted: np.unique).
//     Segment 3 computes rp_m[r] = rp_pos[r] + rp_neg[r] (merged graph).
// ---------------------------------------------------------------------------
__device__ __forceinline__ int lower_bound_v(const int* __restrict__ rows,
                                             int nnz, int r) {
    int lo = 0, hi = nnz;
    while (lo < hi) {
        int mid = (lo + hi) >> 1;
        if (rows[mid] < r) lo = mid + 1; else hi = mid;
    }
    return lo;
}

__global__ void k_row_ptr4(const int* __restrict__ rows_a, int nnz_a, int* __restrict__ pa,
                           const int* __restrict__ rows_b, int nnz_b, int* __restrict__ pb,
                           const int* __restrict__ rows_c, int nnz_c, int* __restrict__ pc,
                           int* __restrict__ pm) {
    int t = blockIdx.x * blockDim.x + threadIdx.x;
    int which = t / (NUM_NODES + 1);
    int r = t - which * (NUM_NODES + 1);
    if (which == 0) pa[r] = lower_bound_v(rows_a, nnz_a, r);
    else if (which == 1) pb[r] = lower_bound_v(rows_b, nnz_b, r);
    else if (which == 2) pc[r] = lower_bound_v(rows_c, nnz_c, r);
    else if (which == 3) pm[r] = lower_bound_v(rows_a, nnz_a, r) +
                                 lower_bound_v(rows_b, nnz_b, r);
}

// ---------------------------------------------------------------------------
// K3: convert user_emb || item_emb (fp32) -> bf16 table (nt loads: read-once)
// ---------------------------------------------------------------------------
__global__ void k_cvt(const float* __restrict__ user_emb,
                      const float* __restrict__ item_emb,
                      u16* __restrict__ emb16) {
    int i = blockIdx.x * blockDim.x + threadIdx.x;   // handles 4 floats
    size_t f = (size_t)i * 4;
    const size_t UTOT = (size_t)NUM_USERS * DIM;
    const size_t TOT = (size_t)NUM_NODES * DIM;
    if (f >= TOT) return;
    f4v v = (f < UTOT) ? __builtin_nontemporal_load((const f4v*)(user_emb + f))
                       : __builtin_nontemporal_load((const f4v*)(item_emb + (f - UTOT)));
    ushort4 o;
    o.x = f2bf(v.x); o.y = f2bf(v.y); o.z = f2bf(v.z); o.w = f2bf(v.w);
    *(ushort4*)(emb16 + f) = o;   // normal store: k_path gathers from this next
}

// ---------------------------------------------------------------------------
// K4: EDGE-PARALLEL merge of pos+neg CSR into one packed pre-scaled stream.
//     pos edge g -> mev[g + rp_neg[row]] = {col,  val}
//     neg edge g -> mev[g + rp_pos[row+1]] = {col, -ALPHA*val}
//     Same values and same per-row order (pos block then neg block) as the
//     previous round -> layer outputs bitwise identical. Fully coalesced
//     reads; writes are monotonic (gaps only at row boundaries).
// ---------------------------------------------------------------------------
__global__ void k_merge_e(const int* __restrict__ row_p, const int* __restrict__ col_p,
                          const float* __restrict__ val_p,
                          const int* __restrict__ row_n, const int* __restrict__ col_n,
                          const float* __restrict__ val_n,
                          const int* __restrict__ rp_p, const int* __restrict__ rp_n,
                          i2v* __restrict__ mev, int E_pos, int E_tot) {
    int g = blockIdx.x * blockDim.x + threadIdx.x;
    if (g >= E_tot) return;
    if (g < E_pos) {
        int r = __builtin_nontemporal_load(row_p + g);
        i2v e;
        e.x = __builtin_nontemporal_load(col_p + g);
        e.y = __float_as_int(__builtin_nontemporal_load(val_p + g));
        __builtin_nontemporal_store(e, mev + (size_t)g + rp_n[r]);
    } else {
        int i = g - E_pos;
        int r = __builtin_nontemporal_load(row_n + i);
        i2v e;
        e.x = __builtin_nontemporal_load(col_n + i);
        e.y = __float_as_int(-ALPHA_C * __builtin_nontemporal_load(val_n + i));
        __builtin_nontemporal_store(e, mev + (size_t)i + rp_p[r + 1]);
    }
}

// ---------------------------------------------------------------------------
// K5: path SpMM with fused row-softmax over packed {col,exp_v} stream.
// ---------------------------------------------------------------------------
__global__ void k_path(const u16* __restrict__ emb16,
                       const i2v* __restrict__ pev,
                       const int* __restrict__ rp,
                       u16* __restrict__ e0) {
    int t = blockIdx.x * blockDim.x + threadIdx.x;
    int row = t >> 3;
    if (row >= NUM_NODES) return;
    int li = threadIdx.x & 7;
    int start = rp[row], end = rp[row + 1];

    float acc[8];
#pragma unroll
    for (int k = 0; k < 8; ++k) acc[k] = 0.f;
    float s = 0.f;

    seg_pipe<true>(pev, start, end, emb16, li, acc, &s);

    float inv = 1.0f / (s + 1e-12f);
    u32 o[4];
#pragma unroll
    for (int k = 0; k < 4; ++k)
        o[k] = (u32)f2bf(acc[2 * k] * inv) | ((u32)f2bf(acc[2 * k + 1] * inv) << 16);
    *((uint4*)(e0 + (size_t)row * DIM) + li) = *(uint4*)o;   // normal: gathered next
}

// ---------------------------------------------------------------------------
// K6: one propagation layer over the merged pre-scaled stream.
//     acc = sum_merged val*x ; res = acc + ALPHA*e_in
//     FINAL=0: write res (bf16) to e_out (normal store: next layer gathers it)
//     FINAL=1: out = 0.25*(e0 + e1 + e_in + res)  (fp32, nt, straight to d_out)
// ---------------------------------------------------------------------------
template <int FINAL>
__global__ void k_layer_t(const u16* __restrict__ e_in,
                          u16* __restrict__ e_out,
                          const u16* __restrict__ e0,
                          const u16* __restrict__ e1,
                          float* __restrict__ out,
                          const int* __restrict__ rp_m,
                          const i2v* __restrict__ mev) {
    int t = blockIdx.x * blockDim.x + threadIdx.x;
    int row = t >> 3;
    if (row >= NUM_NODES) return;
    int li = threadIdx.x & 7;

    // own-row read issued BEFORE the walk (oldest in VMEM queue -> its wait
    // is free; consuming it after the walk costs nothing)
    uint4 eq = *((const uint4*)(e_in + (size_t)row * DIM) + li);

    float acc[8];
#pragma unroll
    for (int k = 0; k < 8; ++k) acc[k] = 0.f;

    seg_pipe<false>(mev, rp_m[row], rp_m[row + 1], e_in, li, acc, nullptr);

    const u32* ep_ = (const u32*)&eq;
    float res[8];
#pragma unroll
    for (int k = 0; k < 4; ++k) {
        res[2 * k]     = acc[2 * k]     + ALPHA_C * lo_bf(ep_[k]);
        res[2 * k + 1] = acc[2 * k + 1] + ALPHA_C * hi_bf(ep_[k]);
    }

    if (FINAL) {
        u4v q0 = __builtin_nontemporal_load((const u4v*)(e0 + (size_t)row * DIM) + li);
        u4v q1 = __builtin_nontemporal_load((const u4v*)(e1 + (size_t)row * DIM) + li);
        float of[8];
#pragma unroll
        for (int k = 0; k < 4; ++k) {
            float lo = res[2 * k]     + lo_bf(ep_[k]) + lo_bf(q0[k]) + lo_bf(q1[k]);
            float hi = res[2 * k + 1] + hi_bf(ep_[k]) + hi_bf(q0[k]) + hi_bf(q1[k]);
            of[2 * k]     = 0.25f * lo;
            of[2 * k + 1] = 0.25f * hi;
        }
        f4v o0, o1;
        o0.x = of[0]; o0.y = of[1]; o0.z = of[2]; o0.w = of[3];
        o1.x = of[4]; o1.y = of[5]; o1.z = of[6]; o1.w = of[7];
        f4v* sp = (f4v*)(out + (size_t)row * DIM) + li * 2;
        __builtin_nontemporal_store(o0, sp);
        __builtin_nontemporal_store(o1, sp + 1);
    } else {
        u32 o[4];
#pragma unroll
        for (int k = 0; k < 4; ++k)
            o[k] = (u32)f2bf(res[2 * k]) | ((u32)f2bf(res[2 * k + 1]) << 16);
        *((uint4*)(e_out + (size_t)row * DIM) + li) = *(uint4*)o;
    }
}

// ---------------------------------------------------------------------------
extern "C" void kernel_launch(void* const* d_in, const int* in_sizes, int n_in,
                              void* d_out, int out_size, void* d_ws, size_t ws_size,
                              hipStream_t stream) {
    const float* user_emb = (const float*)d_in[0];
    const float* item_emb = (const float*)d_in[1];
    const float* theta    = (const float*)d_in[2];
    const int*   pos_row  = (const int*)d_in[3];
    const int*   pos_col  = (const int*)d_in[4];
    const float* pos_val  = (const float*)d_in[5];
    const int*   neg_row  = (const int*)d_in[6];
    const int*   neg_col  = (const int*)d_in[7];
    const float* neg_val  = (const float*)d_in[8];
    const int*   p_row    = (const int*)d_in[9];
    const int*   p_col    = (const int*)d_in[10];
    const float* p_counts = (const float*)d_in[11];
    const int E_pos  = in_sizes[3];
    const int E_neg  = in_sizes[6];
    const int E_path = in_sizes[9];

    // bump allocator over d_ws (256B aligned chunks)
    char* wsb = (char*)d_ws;
    size_t off = 0;
    auto alloc = [&](size_t bytes) -> void* {
        void* p = wsb + off;
        off = (off + bytes + 255) & ~(size_t)255;
        return p;
    };
    i2v*   pev     = (i2v*)alloc((size_t)E_path * sizeof(i2v));
    int*   rp_pos  = (int*)alloc((size_t)(NUM_NODES + 1) * sizeof(int));
    int*   rp_neg  = (int*)alloc((size_t)(NUM_NODES + 1) * sizeof(int));
    int*   rp_path = (int*)alloc((size_t)(NUM_NODES + 1) * sizeof(int));
    int*   rp_m    = (int*)alloc((size_t)(NUM_NODES + 1) * sizeof(int));
    i2v*   mev     = (i2v*)alloc((size_t)(E_pos + E_neg) * sizeof(i2v));
    u16*   emb16   = (u16*)alloc((size_t)NUM_NODES * DIM * sizeof(u16));
    u16*   e0      = (u16*)alloc((size_t)NUM_NODES * DIM * sizeof(u16));
    u16*   e1      = (u16*)alloc((size_t)NUM_NODES * DIM * sizeof(u16));
    u16*   e2      = emb16;   // emb16 is dead after k_path; reuse for e2
    float* outp    = (float*)d_out;

    k_expv_pack<<<(E_path + 255) / 256, 256, 0, stream>>>(p_counts, theta, p_col,
                                                          pev, E_path);

    int total_rp = 4 * (NUM_NODES + 1);
    k_row_ptr4<<<(total_rp + 255) / 256, 256, 0, stream>>>(
        pos_row, E_pos, rp_pos, neg_row, E_neg, rp_neg, p_row, E_path, rp_path,
        rp_m);

    int cvt_threads = (NUM_NODES * DIM) / 4;
    k_cvt<<<(cvt_threads + 255) / 256, 256, 0, stream>>>(user_emb, item_emb, emb16);

    int E_tot = E_pos + E_neg;
    k_merge_e<<<(E_tot + 255) / 256, 256, 0, stream>>>(
        pos_row, pos_col, pos_val, neg_row, neg_col, neg_val,
        rp_pos, rp_neg, mev, E_pos, E_tot);

    // one 8-lane group per row: 32 rows per 256-thread block
    int row_blocks = (NUM_NODES + 31) / 32;  // 3750

    k_path<<<row_blocks, 256, 0, stream>>>(emb16, pev, rp_path, e0);
    k_layer_t<0><<<row_blocks, 256, 0, stream>>>(e0, e1, nullptr, nullptr, nullptr,
                                                 rp_m, mev);
    k_layer_t<0><<<row_blocks, 256, 0, stream>>>(e1, e2, nullptr, nullptr, nullptr,
                                                 rp_m, mev);
    k_layer_t<1><<<row_blocks, 256, 0, stream>>>(e2, nullptr, e0, e1, outp,
                                                 rp_m, mev);
}

// Round 3
// 484.037 us; speedup vs baseline: 1.1642x; 1.1642x over previous
//
#include <hip/hip_runtime.h>

#define NUM_USERS 80000
#define NUM_ITEMS 40000
#define NUM_NODES 120000
#define DIM 64
#define ALPHA_C 0.8f

typedef unsigned short u16;
typedef unsigned int u32;
typedef int   i2v __attribute__((ext_vector_type(2)));
typedef u32   u4v __attribute__((ext_vector_type(4)));
typedef float f4v __attribute__((ext_vector_type(4)));

// fp32 -> bf16 round-nearest-even
__device__ __forceinline__ u16 f2bf(float f) {
    union { float f; u32 i; } v;
    v.f = f;
    u32 i = v.i;
    u32 r = (i + 0x7FFFu + ((i >> 16) & 1u)) >> 16;
    return (u16)r;
}
__device__ __forceinline__ float lo_bf(u32 u) { return __uint_as_float(u << 16); }
__device__ __forceinline__ float hi_bf(u32 u) { return __uint_as_float(u & 0xffff0000u); }

// accumulate 8 bf16 (packed in uint4) * v into acc[8]
__device__ __forceinline__ void acc8(float* __restrict__ acc, float v, uint4 q) {
    const u32* p = (const u32*)&q;
#pragma unroll
    for (int k = 0; k < 4; ++k) {
        u32 u = p[k];
        acc[2 * k]     = fmaf(v, lo_bf(u), acc[2 * k]);
        acc[2 * k + 1] = fmaf(v, hi_bf(u), acc[2 * k + 1]);
    }
}

__device__ __forceinline__ uint4 ldrow(const u16* __restrict__ x, int c, int li) {
    return *((const uint4*)(x + (size_t)c * DIM) + li);
}

// ---------------------------------------------------------------------------
// Depth-4 software-pipelined segment gather over a PACKED {col,val} stream.
// 8-lane group walks its segment. Per iteration: load edge-pair p, issue
// row gathers for pair p-2, consume pair p-4. Edge loads sit 2 iterations
// ahead of their gather so the vmcnt wait for addresses never drains the
// in-flight row gathers.
// NOTE (R2 lesson): edge loads MUST be normal cached loads, not nontemporal.
// The group walks the stream sequentially, so each 64B line is touched 4x;
// nt evict-first re-fetched every touch -> +82 MB FETCH, +33% time.
// If SUMV, also accumulates the sum of val into *vsum (accumulation order
// is exactly edge order 0,1,2,... -- bitwise identical to prior rounds).
// ---------------------------------------------------------------------------
template <bool SUMV>
__device__ __forceinline__ void seg_pipe(const i2v* __restrict__ ep0,
                                         int start, int end,
                                         const u16* __restrict__ x,
                                         int li,
                                         float* __restrict__ acc,
                                         float* __restrict__ vsum) {
    const int n = end - start;
    const i2v* ep = ep0 + start;
    float s = 0.f;
    const int np = n >> 1;
    if (np >= 4) {
        i2v ea0 = ep[0], ea1 = ep[1];
        i2v eb0 = ep[2], eb1 = ep[3];
        i2v ec0 = ep[4], ec1 = ep[5];
        i2v ed0 = ep[6], ed1 = ep[7];
        uint4 xa0 = ldrow(x, ea0.x, li), xa1 = ldrow(x, ea1.x, li);
        uint4 xb0 = ldrow(x, eb0.x, li), xb1 = ldrow(x, eb1.x, li);
        for (int p = 4; p < np; ++p) {
            // E: prefetch edge pair p (2 iterations ahead of its gather)
            i2v ee0 = ep[2 * p];
            i2v ee1 = ep[2 * p + 1];
            // G: issue row gathers for pair p-2 (edges arrived long ago)
            uint4 xc0 = ldrow(x, ec0.x, li);
            uint4 xc1 = ldrow(x, ec1.x, li);
            // C: consume pair p-4 (rows issued 2 iterations ago)
            float va0 = __int_as_float(ea0.y), va1 = __int_as_float(ea1.y);
            acc8(acc, va0, xa0);
            acc8(acc, va1, xa1);
            if (SUMV) s += va0 + va1;
            // shift pipeline
            ea0 = eb0; ea1 = eb1; eb0 = ec0; eb1 = ec1;
            ec0 = ed0; ec1 = ed1; ed0 = ee0; ed1 = ee1;
            xa0 = xb0; xa1 = xb1; xb0 = xc0; xb1 = xc1;
        }
        // drain: pipe holds pairs A(rows xa), B(rows xb), C(cols ec), D(cols ed)
        uint4 xc0 = ldrow(x, ec0.x, li), xc1 = ldrow(x, ec1.x, li);
        uint4 xd0 = ldrow(x, ed0.x, li), xd1 = ldrow(x, ed1.x, li);
        {
            float va0 = __int_as_float(ea0.y), va1 = __int_as_float(ea1.y);
            acc8(acc, va0, xa0); acc8(acc, va1, xa1);
            if (SUMV) s += va0 + va1;
        }
        {
            float vb0 = __int_as_float(eb0.y), vb1 = __int_as_float(eb1.y);
            acc8(acc, vb0, xb0); acc8(acc, vb1, xb1);
            if (SUMV) s += vb0 + vb1;
        }
        {
            float vc0 = __int_as_float(ec0.y), vc1 = __int_as_float(ec1.y);
            acc8(acc, vc0, xc0); acc8(acc, vc1, xc1);
            if (SUMV) s += vc0 + vc1;
        }
        {
            float vd0 = __int_as_float(ed0.y), vd1 = __int_as_float(ed1.y);
            acc8(acc, vd0, xd0); acc8(acc, vd1, xd1);
            if (SUMV) s += vd0 + vd1;
        }
        if (n & 1) {
            i2v eq = ep[n - 1];
            float v = __int_as_float(eq.y);
            uint4 xq = ldrow(x, eq.x, li);
            acc8(acc, v, xq);
            if (SUMV) s += v;
        }
    } else {
        for (int e = 0; e < n; ++e) {
            i2v eq = ep[e];
            float v = __int_as_float(eq.y);
            uint4 xq = ldrow(x, eq.x, li);
            acc8(acc, v, xq);
            if (SUMV) s += v;
        }
    }
    if (SUMV) *vsum = s;
}

// ---------------------------------------------------------------------------
// K1: fused theta-softmax + exp_v + path-stream pack.
//     pev[i] = { p_col[i], exp(dot(p_counts[i,0:6], softmax(theta))) }
//     Every thread recomputes the 6-element softmax (expression-identical to
//     the original two-kernel version -> bitwise-same values).
// ---------------------------------------------------------------------------
__global__ void k_expv_pack(const float* __restrict__ p_counts,
                            const float* __restrict__ theta,
                            const int* __restrict__ p_col,
                            i2v* __restrict__ pev, int E) {
    int i = blockIdx.x * blockDim.x + threadIdx.x;
    if (i >= E) return;
    float m = -1e30f;
    for (int k = 0; k < 6; ++k) m = fmaxf(m, theta[k]);
    float e[6];
    float s = 0.f;
    for (int k = 0; k < 6; ++k) { e[k] = expf(theta[k] - m); s += e[k]; }
    float w0 = e[0] / s, w1 = e[1] / s, w2 = e[2] / s,
          w3 = e[3] / s, w4 = e[4] / s, w5 = e[5] / s;
    const float* c = p_counts + (size_t)i * 6;
    float v = c[0] * w0 + c[1] * w1 + c[2] * w2 +
              c[3] * w3 + c[4] * w4 + c[5] * w5;
    i2v o;
    o.x = __builtin_nontemporal_load(p_col + i);
    o.y = __float_as_int(expf(v));
    __builtin_nontemporal_store(o, pev + i);
}

// ---------------------------------------------------------------------------
// K2: all CSR row_ptr arrays in one launch (rows sorted: np.unique).
//     Segment 3 computes rp_m[r] = rp_pos[r] + rp_neg[r] (merged graph).
// ---------------------------------------------------------------------------
__device__ __forceinline__ int lower_bound_v(const int* __restrict__ rows,
                                             int nnz, int r) {
    int lo = 0, hi = nnz;
    while (lo < hi) {
        int mid = (lo + hi) >> 1;
        if (rows[mid] < r) lo = mid + 1; else hi = mid;
    }
    return lo;
}

__global__ void k_row_ptr4(const int* __restrict__ rows_a, int nnz_a, int* __restrict__ pa,
                           const int* __restrict__ rows_b, int nnz_b, int* __restrict__ pb,
                           const int* __restrict__ rows_c, int nnz_c, int* __restrict__ pc,
                           int* __restrict__ pm) {
    int t = blockIdx.x * blockDim.x + threadIdx.x;
    int which = t / (NUM_NODES + 1);
    int r = t - which * (NUM_NODES + 1);
    if (which == 0) pa[r] = lower_bound_v(rows_a, nnz_a, r);
    else if (which == 1) pb[r] = lower_bound_v(rows_b, nnz_b, r);
    else if (which == 2) pc[r] = lower_bound_v(rows_c, nnz_c, r);
    else if (which == 3) pm[r] = lower_bound_v(rows_a, nnz_a, r) +
                                 lower_bound_v(rows_b, nnz_b, r);
}

// ---------------------------------------------------------------------------
// K3: convert user_emb || item_emb (fp32) -> bf16 table (nt loads: each line
//     read exactly once, whole line per wave -> nt is safe here)
// ---------------------------------------------------------------------------
__global__ void k_cvt(const float* __restrict__ user_emb,
                      const float* __restrict__ item_emb,
                      u16* __restrict__ emb16) {
    int i = blockIdx.x * blockDim.x + threadIdx.x;   // handles 4 floats
    size_t f = (size_t)i * 4;
    const size_t UTOT = (size_t)NUM_USERS * DIM;
    const size_t TOT = (size_t)NUM_NODES * DIM;
    if (f >= TOT) return;
    f4v v = (f < UTOT) ? __builtin_nontemporal_load((const f4v*)(user_emb + f))
                       : __builtin_nontemporal_load((const f4v*)(item_emb + (f - UTOT)));
    ushort4 o;
    o.x = f2bf(v.x); o.y = f2bf(v.y); o.z = f2bf(v.z); o.w = f2bf(v.w);
    *(ushort4*)(emb16 + f) = o;   // normal store: k_path gathers from this next
}

// ---------------------------------------------------------------------------
// K4: EDGE-PARALLEL merge of pos+neg CSR into one packed pre-scaled stream.
//     pos edge g -> mev[g + rp_neg[row]] = {col,  val}
//     neg edge g -> mev[g + rp_pos[row+1]] = {col, -ALPHA*val}
//     Same values and same per-row order (pos block then neg block) as prior
//     rounds -> layer outputs bitwise identical. Fully coalesced reads;
//     writes are monotonic (gaps only at row boundaries).
// ---------------------------------------------------------------------------
__global__ void k_merge_e(const int* __restrict__ row_p, const int* __restrict__ col_p,
                          const float* __restrict__ val_p,
                          const int* __restrict__ row_n, const int* __restrict__ col_n,
                          const float* __restrict__ val_n,
                          const int* __restrict__ rp_p, const int* __restrict__ rp_n,
                          i2v* __restrict__ mev, int E_pos, int E_tot) {
    int g = blockIdx.x * blockDim.x + threadIdx.x;
    if (g >= E_tot) return;
    if (g < E_pos) {
        int r = __builtin_nontemporal_load(row_p + g);
        i2v e;
        e.x = __builtin_nontemporal_load(col_p + g);
        e.y = __float_as_int(__builtin_nontemporal_load(val_p + g));
        __builtin_nontemporal_store(e, mev + (size_t)g + rp_n[r]);
    } else {
        int i = g - E_pos;
        int r = __builtin_nontemporal_load(row_n + i);
        i2v e;
        e.x = __builtin_nontemporal_load(col_n + i);
        e.y = __float_as_int(-ALPHA_C * __builtin_nontemporal_load(val_n + i));
        __builtin_nontemporal_store(e, mev + (size_t)i + rp_p[r + 1]);
    }
}

// ---------------------------------------------------------------------------
// K5: path SpMM with fused row-softmax over packed {col,exp_v} stream.
// ---------------------------------------------------------------------------
__global__ void k_path(const u16* __restrict__ emb16,
                       const i2v* __restrict__ pev,
                       const int* __restrict__ rp,
                       u16* __restrict__ e0) {
    int t = blockIdx.x * blockDim.x + threadIdx.x;
    int row = t >> 3;
    if (row >= NUM_NODES) return;
    int li = threadIdx.x & 7;
    int start = rp[row], end = rp[row + 1];

    float acc[8];
#pragma unroll
    for (int k = 0; k < 8; ++k) acc[k] = 0.f;
    float s = 0.f;

    seg_pipe<true>(pev, start, end, emb16, li, acc, &s);

    float inv = 1.0f / (s + 1e-12f);
    u32 o[4];
#pragma unroll
    for (int k = 0; k < 4; ++k)
        o[k] = (u32)f2bf(acc[2 * k] * inv) | ((u32)f2bf(acc[2 * k + 1] * inv) << 16);
    *((uint4*)(e0 + (size_t)row * DIM) + li) = *(uint4*)o;   // normal: gathered next
}

// ---------------------------------------------------------------------------
// K6: one propagation layer over the merged pre-scaled stream.
//     acc = sum_merged val*x ; res = acc + ALPHA*e_in
//     FINAL=0: write res (bf16) to e_out (normal store: next layer gathers it)
//     FINAL=1: out = 0.25*(e0 + e1 + e_in + res)  (fp32, nt, straight to d_out)
// ---------------------------------------------------------------------------
template <int FINAL>
__global__ void k_layer_t(const u16* __restrict__ e_in,
                          u16* __restrict__ e_out,
                          const u16* __restrict__ e0,
                          const u16* __restrict__ e1,
                          float* __restrict__ out,
                          const int* __restrict__ rp_m,
                          const i2v* __restrict__ mev) {
    int t = blockIdx.x * blockDim.x + threadIdx.x;
    int row = t >> 3;
    if (row >= NUM_NODES) return;
    int li = threadIdx.x & 7;

    // own-row read issued BEFORE the walk (oldest in VMEM queue -> its wait
    // is free; consuming it after the walk costs nothing)
    uint4 eq = *((const uint4*)(e_in + (size_t)row * DIM) + li);

    float acc[8];
#pragma unroll
    for (int k = 0; k < 8; ++k) acc[k] = 0.f;

    seg_pipe<false>(mev, rp_m[row], rp_m[row + 1], e_in, li, acc, nullptr);

    const u32* ep_ = (const u32*)&eq;
    float res[8];
#pragma unroll
    for (int k = 0; k < 4; ++k) {
        res[2 * k]     = acc[2 * k]     + ALPHA_C * lo_bf(ep_[k]);
        res[2 * k + 1] = acc[2 * k + 1] + ALPHA_C * hi_bf(ep_[k]);
    }

    if (FINAL) {
        u4v q0 = __builtin_nontemporal_load((const u4v*)(e0 + (size_t)row * DIM) + li);
        u4v q1 = __builtin_nontemporal_load((const u4v*)(e1 + (size_t)row * DIM) + li);
        float of[8];
#pragma unroll
        for (int k = 0; k < 4; ++k) {
            float lo = res[2 * k]     + lo_bf(ep_[k]) + lo_bf(q0[k]) + lo_bf(q1[k]);
            float hi = res[2 * k + 1] + hi_bf(ep_[k]) + hi_bf(q0[k]) + hi_bf(q1[k]);
            of[2 * k]     = 0.25f * lo;
            of[2 * k + 1] = 0.25f * hi;
        }
        f4v o0, o1;
        o0.x = of[0]; o0.y = of[1]; o0.z = of[2]; o0.w = of[3];
        o1.x = of[4]; o1.y = of[5]; o1.z = of[6]; o1.w = of[7];
        f4v* sp = (f4v*)(out + (size_t)row * DIM) + li * 2;
        __builtin_nontemporal_store(o0, sp);
        __builtin_nontemporal_store(o1, sp + 1);
    } else {
        u32 o[4];
#pragma unroll
        for (int k = 0; k < 4; ++k)
            o[k] = (u32)f2bf(res[2 * k]) | ((u32)f2bf(res[2 * k + 1]) << 16);
        *((uint4*)(e_out + (size_t)row * DIM) + li) = *(uint4*)o;
    }
}

// ---------------------------------------------------------------------------
extern "C" void kernel_launch(void* const* d_in, const int* in_sizes, int n_in,
                              void* d_out, int out_size, void* d_ws, size_t ws_size,
                              hipStream_t stream) {
    const float* user_emb = (const float*)d_in[0];
    const float* item_emb = (const float*)d_in[1];
    const float* theta    = (const float*)d_in[2];
    const int*   pos_row  = (const int*)d_in[3];
    const int*   pos_col  = (const int*)d_in[4];
    const float* pos_val  = (const float*)d_in[5];
    const int*   neg_row  = (const int*)d_in[6];
    const int*   neg_col  = (const int*)d_in[7];
    const float* neg_val  = (const float*)d_in[8];
    const int*   p_row    = (const int*)d_in[9];
    const int*   p_col    = (const int*)d_in[10];
    const float* p_counts = (const float*)d_in[11];
    const int E_pos  = in_sizes[3];
    const int E_neg  = in_sizes[6];
    const int E_path = in_sizes[9];

    // bump allocator over d_ws (256B aligned chunks)
    char* wsb = (char*)d_ws;
    size_t off = 0;
    auto alloc = [&](size_t bytes) -> void* {
        void* p = wsb + off;
        off = (off + bytes + 255) & ~(size_t)255;
        return p;
    };
    i2v*   pev     = (i2v*)alloc((size_t)E_path * sizeof(i2v));
    int*   rp_pos  = (int*)alloc((size_t)(NUM_NODES + 1) * sizeof(int));
    int*   rp_neg  = (int*)alloc((size_t)(NUM_NODES + 1) * sizeof(int));
    int*   rp_path = (int*)alloc((size_t)(NUM_NODES + 1) * sizeof(int));
    int*   rp_m    = (int*)alloc((size_t)(NUM_NODES + 1) * sizeof(int));
    i2v*   mev     = (i2v*)alloc((size_t)(E_pos + E_neg) * sizeof(i2v));
    u16*   emb16   = (u16*)alloc((size_t)NUM_NODES * DIM * sizeof(u16));
    u16*   e0      = (u16*)alloc((size_t)NUM_NODES * DIM * sizeof(u16));
    u16*   e1      = (u16*)alloc((size_t)NUM_NODES * DIM * sizeof(u16));
    u16*   e2      = emb16;   // emb16 is dead after k_path; reuse for e2
    float* outp    = (float*)d_out;

    k_expv_pack<<<(E_path + 255) / 256, 256, 0, stream>>>(p_counts, theta, p_col,
                                                          pev, E_path);

    int total_rp = 4 * (NUM_NODES + 1);
    k_row_ptr4<<<(total_rp + 255) / 256, 256, 0, stream>>>(
        pos_row, E_pos, rp_pos, neg_row, E_neg, rp_neg, p_row, E_path, rp_path,
        rp_m);

    int cvt_threads = (NUM_NODES * DIM) / 4;
    k_cvt<<<(cvt_threads + 255) / 256, 256, 0, stream>>>(user_emb, item_emb, emb16);

    int E_tot = E_pos + E_neg;
    k_merge_e<<<(E_tot + 255) / 256, 256, 0, stream>>>(
        pos_row, pos_col, pos_val, neg_row, neg_col, neg_val,
        rp_pos, rp_neg, mev, E_pos, E_tot);

    // one 8-lane group per row: 32 rows per 256-thread block
    int row_blocks = (NUM_NODES + 31) / 32;  // 3750

    k_path<<<row_blocks, 256, 0, stream>>>(emb16, pev, rp_path, e0);
    k_layer_t<0><<<row_blocks, 256, 0, stream>>>(e0, e1, nullptr, nullptr, nullptr,
                                                 rp_m, mev);
    k_layer_t<0><<<row_blocks, 256, 0, stream>>>(e1, e2, nullptr, nullptr, nullptr,
                                                 rp_m, mev);
    k_layer_t<1><<<row_blocks, 256, 0, stream>>>(e2, nullptr, e0, e1, outp,
                                                 rp_m, mev);
}